// Round 16
// baseline (314.953 us; speedup 1.0000x reference)
//
#include <hip/hip_runtime.h>
#include <math.h>

#define NN 50000
#define NE 800000
#define ET (NE + NN)     // edges + self-loops
#define DF 101
#define HP 104           // padded bf16 row stride (52 uints, 4B-aligned)
#define NEG 0.2f
#define MAXK 8           // gat_agg: supports in-degree up to 8*64=512

// MFMA gemm tiling
#define GM 64            // rows per block
#define KP 128           // K padded (101 -> 128)
#define NP 112           // N padded (101 -> 112, 7 tiles of 16)
#define LSTR 136         // LDS row stride in ushorts (128 + 8 pad)

typedef __attribute__((ext_vector_type(8))) short bf16x8;
typedef __attribute__((ext_vector_type(4))) float f32x4;

// float -> bf16 round-to-nearest-even
__device__ __forceinline__ unsigned short f2bf(float f) {
    unsigned u = __float_as_uint(f);
    unsigned r = u + 0x7FFFu + ((u >> 16) & 1u);
    return (unsigned short)(r >> 16);
}
__device__ __forceinline__ float bflo(unsigned v) { return __uint_as_float(v << 16); }
__device__ __forceinline__ float bfhi(unsigned v) { return __uint_as_float(v & 0xFFFF0000u); }

// ---- prep: Wt bf16 [NP][KP], transposed + zero-padded ----
__global__ void prep_wt(const float* __restrict__ W, unsigned short* __restrict__ wtb) {
    int i = blockIdx.x * 256 + threadIdx.x;
    if (i >= NP * KP) return;
    int c = i >> 7;          // output col (N)
    int k = i & (KP - 1);
    float v = (c < DF && k < DF) ? W[k * DF + c] : 0.f;
    wtb[c * KP + k] = f2bf(v);
}

// ---- h16 = bf16(x @ W) via MFMA + fused alpha_s/alpha_d epilogue ----
__global__ __launch_bounds__(256) void gemm_h(
    const float* __restrict__ x, const unsigned short* __restrict__ wtb,
    const float* __restrict__ a_s, const float* __restrict__ a_d,
    unsigned short* __restrict__ h16,
    float* __restrict__ alpha_s, float* __restrict__ alpha_d)
{
    __shared__ unsigned short xs[GM * LSTR];   // 17408 B
    __shared__ unsigned short ws[NP * LSTR];   // 30464 B
    __shared__ float asv[NP], adv[NP];
    const int t = threadIdx.x;
    const int row0 = blockIdx.x * GM;

    if (t < NP) {
        asv[t] = (t < DF) ? a_s[t] : 0.f;
        adv[t] = (t < DF) ? a_d[t] : 0.f;
    }
    // stage Wt (bf16, linear rows of 128 -> padded LDS rows)
    {
        const uint4* src = (const uint4*)wtb;           // [NP][16] uint4
        for (int i = t; i < NP * 16; i += 256) {
            int r = i >> 4, seg = i & 15;
            uint4 v = src[r * 16 + seg];
            *(uint4*)&ws[r * LSTR + seg * 8] = v;
        }
    }
    // stage x tile, f32 -> bf16, zero pad (k>=DF or row>=NN)
    for (int i = t; i < GM * KP; i += 256) {
        int r = i >> 7, k = i & (KP - 1);
        int row = row0 + r;
        float v = (k < DF && row < NN) ? x[(size_t)row * DF + k] : 0.f;
        xs[r * LSTR + k] = f2bf(v);
    }
    __syncthreads();

    const int wv = t >> 6, lane = t & 63;
    const int arow = wv * 16 + (lane & 15);
    const int kgrp = (lane >> 4) * 8;

    bf16x8 a[4];
    #pragma unroll
    for (int ks = 0; ks < 4; ++ks)
        a[ks] = *(const bf16x8*)&xs[arow * LSTR + ks * 32 + kgrp];

    float pas[4] = {0.f, 0.f, 0.f, 0.f};
    float pad_[4] = {0.f, 0.f, 0.f, 0.f};
    const int rbase = row0 + wv * 16 + (lane >> 4) * 4;

    #pragma unroll
    for (int nt = 0; nt < 7; ++nt) {
        f32x4 acc = {0.f, 0.f, 0.f, 0.f};
        const int col = nt * 16 + (lane & 15);
        #pragma unroll
        for (int ks = 0; ks < 4; ++ks) {
            bf16x8 b = *(const bf16x8*)&ws[col * LSTR + ks * 32 + kgrp];
            acc = __builtin_amdgcn_mfma_f32_16x16x32_bf16(a[ks], b, acc, 0, 0, 0);
        }
        const float av = asv[col], dv = adv[col];   // zero beyond DF
        #pragma unroll
        for (int r = 0; r < 4; ++r) {
            int row = rbase + r;
            if (col < HP && row < NN)                      // cols 101..103 are 0
                h16[(size_t)row * HP + col] = f2bf(acc[r]);
            pas[r]  = fmaf(acc[r], av, pas[r]);
            pad_[r] = fmaf(acc[r], dv, pad_[r]);
        }
    }

    // reduce alpha partials across the 16-lane column group
    #pragma unroll
    for (int off = 1; off < 16; off <<= 1) {
        #pragma unroll
        for (int r = 0; r < 4; ++r) {
            pas[r]  += __shfl_xor(pas[r],  off);
            pad_[r] += __shfl_xor(pad_[r], off);
        }
    }
    if ((lane & 15) == 0) {
        #pragma unroll
        for (int r = 0; r < 4; ++r) {
            int row = rbase + r;
            if (row < NN) { alpha_s[row] = pas[r]; alpha_d[row] = pad_[r]; }
        }
    }
}

// ================= CSR build (once per launch; reused by both layers) =======

__global__ void count_rank(const int* __restrict__ ei, int* __restrict__ deg,
                           unsigned short* __restrict__ rank) {
    int i = blockIdx.x * blockDim.x + threadIdx.x;
    if (i >= ET) return;
    int d = (i < NE) ? ei[NE + i] : (i - NE);
    rank[i] = (unsigned short)atomicAdd(&deg[d], 1);
}

__global__ __launch_bounds__(256) void scanA(const int* __restrict__ deg,
                                             int* __restrict__ part, int* __restrict__ aux) {
    __shared__ int sh[256];
    int t = threadIdx.x;
    int i = blockIdx.x * 256 + t;
    int v = (i < NN) ? deg[i] : 0;
    sh[t] = v; __syncthreads();
    #pragma unroll
    for (int off = 1; off < 256; off <<= 1) {
        int u = (t >= off) ? sh[t - off] : 0;
        __syncthreads();
        sh[t] += u;
        __syncthreads();
    }
    if (i < NN) part[i] = sh[t];
    if (t == 255) aux[blockIdx.x] = sh[255];
}

__global__ __launch_bounds__(256) void scanB(const int* __restrict__ aux,
                                             int* __restrict__ auxex, int nb) {
    __shared__ int sh[256];
    int t = threadIdx.x;
    int v = (t < nb) ? aux[t] : 0;
    sh[t] = v; __syncthreads();
    #pragma unroll
    for (int off = 1; off < 256; off <<= 1) {
        int u = (t >= off) ? sh[t - off] : 0;
        __syncthreads();
        sh[t] += u;
        __syncthreads();
    }
    if (t < nb) auxex[t] = sh[t] - v;
}

__global__ void scanC(const int* __restrict__ part, const int* __restrict__ auxex,
                      int* __restrict__ rowptr) {
    int i = blockIdx.x * blockDim.x + threadIdx.x;
    if (i == 0) rowptr[0] = 0;
    if (i < NN) rowptr[i + 1] = part[i] + auxex[i >> 8];
}

__global__ void scatter_plain(const int* __restrict__ ei, const int* __restrict__ rowptr,
                              const unsigned short* __restrict__ rank,
                              int* __restrict__ srclist) {
    int i = blockIdx.x * blockDim.x + threadIdx.x;
    if (i >= ET) return;
    int s, d;
    if (i < NE) { s = ei[i]; d = ei[NE + i]; } else { s = d = i - NE; }
    srclist[rowptr[d] + rank[i]] = s;     // no atomic, no dependent chain
}

// ========== fused softmax + aggregate (bf16 h gather): wave per dst =========
__global__ __launch_bounds__(256) void gat_agg(
    const int* __restrict__ rowptr, const int* __restrict__ srclist,
    const float* __restrict__ a_s, const float* __restrict__ a_d,
    const unsigned short* __restrict__ h16, const float* __restrict__ bias,
    float* __restrict__ out)
{
    __shared__ __align__(16) uint2 ls[4][64];   // per-wave packed (coef, src)
    const int wv = threadIdx.x >> 6;
    int d = blockIdx.x * 4 + wv;
    if (d >= NN) return;
    int lane = threadIdx.x & 63;
    int s0 = rowptr[d], s1 = rowptr[d + 1];
    float ad = a_d[d];

    float earr[MAXK];
    int mysrc[MAXK];
    float mymax = -INFINITY;
    #pragma unroll
    for (int k = 0; k < MAXK; ++k) {
        int j = s0 + lane + k * 64;
        if (j < s1) {
            int s = srclist[j];
            mysrc[k] = s;
            float e = a_s[s] + ad;
            e = e > 0.f ? e : NEG * e;
            earr[k] = e;
            mymax = fmaxf(mymax, e);
        }
    }
    #pragma unroll
    for (int off = 32; off; off >>= 1)
        mymax = fmaxf(mymax, __shfl_xor(mymax, off));

    float sum = 0.f;
    #pragma unroll
    for (int k = 0; k < MAXK; ++k) {
        int j = s0 + lane + k * 64;
        if (j < s1) {
            float w = __expf(earr[k] - mymax);
            earr[k] = w;
            sum += w;
        }
    }
    #pragma unroll
    for (int off = 32; off; off >>= 1)
        sum += __shfl_xor(sum, off);
    float invz = 1.f / (sum + 1e-16f);

    const int li = (lane < 51) ? lane : 51;   // lanes >=52 read pad zeros
    float acc0 = 0.f, acc1 = 0.f;
    #pragma unroll
    for (int k = 0; k < MAXK; ++k) {
        int jb = s0 + k * 64;
        if (jb >= s1) break;
        int lim = s1 - jb; if (lim > 64) lim = 64;
        ls[wv][lane] = make_uint2(__float_as_uint(earr[k] * invz),
                                  (unsigned)mysrc[k]);   // wave-sync LDS exchange

        int i = 0;
        for (; i + 16 <= lim; i += 16) {     // 16 gathers in flight
            unsigned vv[16]; float cc[16];
            #pragma unroll
            for (int u = 0; u < 8; ++u) {
                uint4 q = *(const uint4*)&ls[wv][i + 2 * u];
                cc[2*u]   = __uint_as_float(q.x);
                cc[2*u+1] = __uint_as_float(q.z);
                vv[2*u]   = *((const unsigned*)(h16 + (size_t)q.y * HP) + li);
                vv[2*u+1] = *((const unsigned*)(h16 + (size_t)q.w * HP) + li);
            }
            #pragma unroll
            for (int u = 0; u < 16; ++u) {
                acc0 = fmaf(cc[u], bflo(vv[u]), acc0);
                acc1 = fmaf(cc[u], bfhi(vv[u]), acc1);
            }
        }
        for (; i + 8 <= lim; i += 8) {
            unsigned vv[8]; float cc[8];
            #pragma unroll
            for (int u = 0; u < 4; ++u) {
                uint4 q = *(const uint4*)&ls[wv][i + 2 * u];
                cc[2*u]   = __uint_as_float(q.x);
                cc[2*u+1] = __uint_as_float(q.z);
                vv[2*u]   = *((const unsigned*)(h16 + (size_t)q.y * HP) + li);
                vv[2*u+1] = *((const unsigned*)(h16 + (size_t)q.w * HP) + li);
            }
            #pragma unroll
            for (int u = 0; u < 8; ++u) {
                acc0 = fmaf(cc[u], bflo(vv[u]), acc0);
                acc1 = fmaf(cc[u], bfhi(vv[u]), acc1);
            }
        }
        for (; i + 4 <= lim; i += 4) {
            uint4 q0 = *(const uint4*)&ls[wv][i];
            uint4 q1 = *(const uint4*)&ls[wv][i + 2];
            unsigned v0 = *((const unsigned*)(h16 + (size_t)q0.y * HP) + li);
            unsigned v1 = *((const unsigned*)(h16 + (size_t)q0.w * HP) + li);
            unsigned v2 = *((const unsigned*)(h16 + (size_t)q1.y * HP) + li);
            unsigned v3 = *((const unsigned*)(h16 + (size_t)q1.w * HP) + li);
            float c0 = __uint_as_float(q0.x), c1 = __uint_as_float(q0.z);
            float c2 = __uint_as_float(q1.x), c3 = __uint_as_float(q1.z);
            acc0 = fmaf(c0, bflo(v0), acc0); acc1 = fmaf(c0, bfhi(v0), acc1);
            acc0 = fmaf(c1, bflo(v1), acc0); acc1 = fmaf(c1, bfhi(v1), acc1);
            acc0 = fmaf(c2, bflo(v2), acc0); acc1 = fmaf(c2, bfhi(v2), acc1);
            acc0 = fmaf(c3, bflo(v3), acc0); acc1 = fmaf(c3, bfhi(v3), acc1);
        }
        for (; i < lim; ++i) {
            uint2 p = ls[wv][i];
            unsigned v = *((const unsigned*)(h16 + (size_t)p.y * HP) + li);
            float c = __uint_as_float(p.x);
            acc0 = fmaf(c, bflo(v), acc0);
            acc1 = fmaf(c, bfhi(v), acc1);
        }
    }
    int c0 = 2 * lane;
    if (c0 < DF)     out[(size_t)d * DF + c0]     = acc0 + bias[c0];
    if (c0 + 1 < DF) out[(size_t)d * DF + c0 + 1] = acc1 + bias[c0 + 1];
}

static inline size_t alignup(size_t v) { return (v + 255) & ~size_t(255); }

extern "C" void kernel_launch(void* const* d_in, const int* in_sizes, int n_in,
                              void* d_out, int out_size, void* d_ws, size_t ws_size,
                              hipStream_t stream)
{
    const float* x    = (const float*)d_in[0];
    const int*   ei   = (const int*)  d_in[1];   // [2, NE]
    const float* Ws   = (const float*)d_in[2];   // [L, D, D]
    const float* a_s  = (const float*)d_in[3];   // [L, D]
    const float* a_d  = (const float*)d_in[4];   // [L, D]
    const float* bias = (const float*)d_in[5];   // [L, D]
    float* out = (float*)d_out;

    char* w = (char*)d_ws;
    unsigned short* h16  = (unsigned short*)w; w += alignup((size_t)NN * HP * 2);
    float* x1      = (float*)w; w += alignup((size_t)NN * DF * 4);
    int*   srclist = (int*)w;   w += alignup((size_t)ET * 4);
    unsigned short* rank = (unsigned short*)w; w += alignup((size_t)ET * 2);
    unsigned short* wtb0 = (unsigned short*)w; w += alignup((size_t)NP * KP * 2);
    unsigned short* wtb1 = (unsigned short*)w; w += alignup((size_t)NP * KP * 2);
    float* as_n    = (float*)w; w += alignup((size_t)NN * 4);
    float* ad_n    = (float*)w; w += alignup((size_t)NN * 4);
    int*   deg     = (int*)w;   w += alignup((size_t)NN * 4);
    int*   part    = (int*)w;   w += alignup((size_t)NN * 4);
    int*   rowptr  = (int*)w;   w += alignup((size_t)(NN + 1) * 4);
    int*   aux     = (int*)w;   w += alignup(256 * 4);
    int*   auxex   = (int*)w;   w += alignup(256 * 4);

    const int NB = (NN + 255) / 256;   // 196 scan blocks
    const int NWT = (NP * KP + 255) / 256;

    // weight prep (layer-independent of node data)
    prep_wt<<<NWT, 256, 0, stream>>>(Ws,               wtb0);
    prep_wt<<<NWT, 256, 0, stream>>>(Ws + DF * DF,     wtb1);

    // CSR build: rank-recording count, scan, atomic-free scatter
    hipMemsetAsync(deg, 0, (size_t)NN * 4, stream);
    count_rank<<<(ET + 255) / 256, 256, 0, stream>>>(ei, deg, rank);
    scanA<<<NB, 256, 0, stream>>>(deg, part, aux);
    scanB<<<1, 256, 0, stream>>>(aux, auxex, NB);
    scanC<<<NB, 256, 0, stream>>>(part, auxex, rowptr);
    scatter_plain<<<(ET + 255) / 256, 256, 0, stream>>>(ei, rowptr, rank, srclist);

    for (int l = 0; l < 2; ++l) {
        const float* curx = (l == 0) ? x : x1;
        float*       nxt  = (l == 0) ? x1 : out;
        const unsigned short* wtb = (l == 0) ? wtb0 : wtb1;

        gemm_h<<<(NN + GM - 1) / GM, 256, 0, stream>>>(
            curx, wtb, a_s + l * DF, a_d + l * DF, h16, as_n, ad_n);
        gat_agg<<<(NN + 3) / 4, 256, 0, stream>>>(rowptr, srclist, as_n, ad_n,
                                                  h16, bias + l * DF, nxt);
    }
}